// Round 6
// baseline (259.618 us; speedup 1.0000x reference)
//
#include <hip/hip_runtime.h>
#include <math.h>

#define C 4096

typedef float f4 __attribute__((ext_vector_type(4)));

// ---------------------------------------------------------------------------
// REVERT to the verified round-4 two-kernel structure. Round 5's cooperative
// single-kernel variant silently launched nothing (out == memset zeros =>
// hipLaunchCooperativeKernel error path, return code unchecked). The fusion
// hypothesis it was testing is already refuted by r3->r4 (removing a kernel
// boundary moved end-to-end by ~0), so the cooperative path is abandoned
// rather than debugged.
//
// Session conclusion state: matvec3 = 68-70 us = 2.96 TB/s aggregate weight
// read = ~94% of the measured per-direction fabric ceiling (m13: 6.29 TB/s
// copy = ~3.15 TB/s/direction); invariant across burst/stream/occupancy
// variants (r0-r4). Phase B is the same pattern on ow (~30 us). The 268 MB
// of fp32 weight reads per call is the mandatory-bytes floor.
// ---------------------------------------------------------------------------
__global__ __launch_bounds__(256, 6) void matvec3_kernel(
    const float* __restrict__ kw, const float* __restrict__ vw, const float* __restrict__ rw,
    const float* __restrict__ x, const float* __restrict__ state,
    const float* __restrict__ tmk, const float* __restrict__ tmv, const float* __restrict__ tmr,
    float* __restrict__ kk, float* __restrict__ vvo, float* __restrict__ rr) {
    __shared__ f4 xs[C / 4];   // 16 KiB: mixed input vector

    const int t = threadIdx.x;
    const int m = blockIdx.x >> 9;   // 512 blocks per matrix

    const float* W;
    const float* tm;
    float* out;
    if (m == 0)      { W = kw; tm = tmk; out = kk;  }
    else if (m == 1) { W = vw; tm = tmv; out = vvo; }
    else             { W = rw; tm = tmr; out = rr;  }

    // Stage mixed vector: xm = x*tm + state*(1-tm)
    const f4* x4 = (const f4*)x;
    const f4* s4 = (const f4*)state;
    const f4* t4 = (const f4*)tm;
#pragma unroll
    for (int j = 0; j < 4; ++j) {
        int i = j * 256 + t;
        f4 xi = x4[i], si = s4[i], ti = t4[i];
        f4 r;
        r.x = xi.x * ti.x + si.x * (1.0f - ti.x);
        r.y = xi.y * ti.y + si.y * (1.0f - ti.y);
        r.z = xi.z * ti.z + si.z * (1.0f - ti.z);
        r.w = xi.w * ti.w + si.w * (1.0f - ti.w);
        xs[i] = r;
    }
    __syncthreads();

    const int wave = t >> 6;
    const int lane = t & 63;
    const int r0 = (blockIdx.x & 511) * 8 + wave * 2;
    const int r1 = r0 + 1;
    const f4* W0 = (const f4*)(W + (size_t)r0 * C);
    const f4* W1 = (const f4*)(W + (size_t)r1 * C);

    f4 acc0 = {0.f, 0.f, 0.f, 0.f};
    f4 acc1 = {0.f, 0.f, 0.f, 0.f};
#pragma unroll
    for (int it = 0; it < 16; ++it) {
        f4 w0 = W0[it * 64 + lane];
        f4 w1 = W1[it * 64 + lane];
        f4 xx = xs[it * 64 + lane];
        acc0.x += w0.x * xx.x; acc0.y += w0.y * xx.y;
        acc0.z += w0.z * xx.z; acc0.w += w0.w * xx.w;
        acc1.x += w1.x * xx.x; acc1.y += w1.y * xx.y;
        acc1.z += w1.z * xx.z; acc1.w += w1.w * xx.w;
    }
    float sum0 = (acc0.x + acc0.y) + (acc0.z + acc0.w);
    float sum1 = (acc1.x + acc1.y) + (acc1.z + acc1.w);
#pragma unroll
    for (int off = 32; off > 0; off >>= 1) {
        sum0 += __shfl_down(sum0, off, 64);
        sum1 += __shfl_down(sum1, off, 64);
    }
    if (lane == 0) { out[r0] = sum0; out[r1] = sum1; }
}

// ---------------------------------------------------------------------------
// Kernel 2 (fused): WKV elementwise core computed per-block straight into the
// LDS x-stage, then ow @ (r*wkv). Block 0 also writes the state outputs.
// Grid: 1024 blocks (4/CU), 4 rows/block, 1 row per wave, burst-16 core.
// ---------------------------------------------------------------------------
__global__ __launch_bounds__(256) void wkv_matvec_kernel(
    const float* __restrict__ W,
    const float* __restrict__ kk, const float* __restrict__ vv, const float* __restrict__ rr,
    const float* __restrict__ aa, const float* __restrict__ bb, const float* __restrict__ pp,
    const float* __restrict__ time_first, const float* __restrict__ time_decay,
    const float* __restrict__ x,
    float* __restrict__ out, float* __restrict__ new_state,
    float* __restrict__ out_sa, float* __restrict__ out_sb, float* __restrict__ out_sp) {
    __shared__ f4 xs[C / 4];   // 16 KiB: r * wkv
    const int t = threadIdx.x;
    const bool writer = (blockIdx.x == 0);

    const f4* kk4 = (const f4*)kk;
    const f4* vv4 = (const f4*)vv;
    const f4* rr4 = (const f4*)rr;
    const f4* aa4 = (const f4*)aa;
    const f4* bb4 = (const f4*)bb;
    const f4* pp4 = (const f4*)pp;
    const f4* tf4 = (const f4*)time_first;
    const f4* td4 = (const f4*)time_decay;
    const f4* x4  = (const f4*)x;
    f4* sa4 = (f4*)out_sa;
    f4* sb4 = (f4*)out_sb;
    f4* sp4 = (f4*)out_sp;
    f4* ns4 = (f4*)new_state;

#pragma unroll
    for (int j = 0; j < 4; ++j) {
        int i = j * 256 + t;
        f4 kf = kk4[i], vf = vv4[i], rf = rr4[i];
        f4 af = aa4[i], bf = bb4[i], pf = pp4[i];
        f4 tff = tf4[i], tdf = td4[i];
        f4 rwkv, sa, sb, sp;

#define WKV1(cc)                                                             \
        {                                                                    \
            float k = kf.cc, v = vf.cc;                                      \
            float A = af.cc, B = bf.cc, P = pf.cc;                           \
            float ww = tff.cc + k;                                           \
            float p  = fmaxf(P, ww);                                         \
            float e1 = expf(P - p);                                          \
            float e2 = expf(ww - p);                                         \
            float a  = e1 * A + e2 * v;                                      \
            float b  = e1 * B + e2;                                          \
            float ww2 = P + tdf.cc;                                          \
            float p2  = fmaxf(ww2, k);                                       \
            float e1b = expf(ww2 - p2);                                      \
            float e2b = expf(k - p2);                                        \
            sa.cc = e1b * A + e2b * v;                                       \
            sb.cc = e1b * B + e2b;                                           \
            sp.cc = p2;                                                      \
            float r = 1.0f / (1.0f + expf(-rf.cc));                          \
            rwkv.cc = r * (a / b);                                           \
        }
        WKV1(x) WKV1(y) WKV1(z) WKV1(w)
#undef WKV1

        xs[i] = rwkv;
        if (writer) {
            sa4[i] = sa;
            sb4[i] = sb;
            sp4[i] = sp;
            ns4[i] = x4[i];
        }
    }
    __syncthreads();

    const int wave = t >> 6;
    const int lane = t & 63;
    const int row  = blockIdx.x * 4 + wave;
    const f4* Wrow = (const f4*)(W + (size_t)row * C);

    f4 wreg[16];
#pragma unroll
    for (int it = 0; it < 16; ++it) wreg[it] = Wrow[it * 64 + lane];

    float s0 = 0.f, s1 = 0.f, s2 = 0.f, s3 = 0.f;
#pragma unroll
    for (int it = 0; it < 16; ++it) {
        f4 xx = xs[it * 64 + lane];
        f4 w  = wreg[it];
        s0 += w.x * xx.x;
        s1 += w.y * xx.y;
        s2 += w.z * xx.z;
        s3 += w.w * xx.w;
    }
    float sum = (s0 + s1) + (s2 + s3);
#pragma unroll
    for (int off = 32; off > 0; off >>= 1) sum += __shfl_down(sum, off, 64);
    if (lane == 0) out[row] = sum;
}

// ---------------------------------------------------------------------------
extern "C" void kernel_launch(void* const* d_in, const int* in_sizes, int n_in,
                              void* d_out, int out_size, void* d_ws, size_t ws_size,
                              hipStream_t stream) {
    const float* x          = (const float*)d_in[0];
    const float* state      = (const float*)d_in[1];
    const float* state_a    = (const float*)d_in[2];
    const float* state_b    = (const float*)d_in[3];
    const float* state_p    = (const float*)d_in[4];
    const float* tmk        = (const float*)d_in[5];
    const float* tmv        = (const float*)d_in[6];
    const float* tmr        = (const float*)d_in[7];
    const float* time_first = (const float*)d_in[8];
    const float* time_decay = (const float*)d_in[9];
    const float* kw         = (const float*)d_in[10];
    const float* vw         = (const float*)d_in[11];
    const float* rw         = (const float*)d_in[12];
    const float* ow         = (const float*)d_in[13];

    float* out       = (float*)d_out;        // [0:C)     out
    float* new_state = out + C;              // [C:2C)    new_state = x
    float* new_sa    = out + 2 * C;          // [2C:3C)   new_state_a
    float* new_sb    = out + 3 * C;          // [3C:4C)   new_state_b
    float* new_sp    = out + 4 * C;          // [4C:5C)   new_state_p

    float* ws = (float*)d_ws;
    float* kk = ws;
    float* vv = ws + C;
    float* rr = ws + 2 * C;

    // 1536 blocks = 6/CU; 512 blocks per matrix, 8 rows per block.
    matvec3_kernel<<<3 * C / 8, 256, 0, stream>>>(kw, vw, rw, x, state, tmk, tmv, tmr,
                                                  kk, vv, rr);

    // 1024 blocks = 4/CU; wkv prologue + ow matvec, 1 row per wave.
    wkv_matvec_kernel<<<C / 4, 256, 0, stream>>>(ow, kk, vv, rr,
                                                 state_a, state_b, state_p,
                                                 time_first, time_decay, x,
                                                 out, new_state, new_sa, new_sb, new_sp);
}